// Round 4
// baseline (3962.141 us; speedup 1.0000x reference)
//
#include <hip/hip_runtime.h>
#include <hip/hip_bf16.h>

#define BATCH 32
#define SEQ   512
#define IND   1024
#define HD    1024
#define ZD    2048   // IN + H
#define NG    4096   // 4*H
#define WG_ELEMS (1024 * 2048)   // elements per gate weight matrix
#define PBLK 128                 // persistent grid size

typedef short  shortx8 __attribute__((ext_vector_type(8)));
typedef float  floatx4 __attribute__((ext_vector_type(4)));

#define MFMA16(a, b, c) __builtin_amdgcn_mfma_f32_16x16x32_bf16((a), (b), (c), 0, 0, 0)

__device__ __forceinline__ float sigmoidf_(float x) {
    return 1.0f / (1.0f + __expf(-x));
}
__device__ __forceinline__ float tanhf_(float x) {
    return 1.0f - 2.0f / (__expf(2.0f * x) + 1.0f);
}

__device__ __forceinline__ short bf16s(float x) {
    __hip_bfloat16 h = __float2bfloat16(x);
    return *reinterpret_cast<short*>(&h);
}

__device__ __forceinline__ shortx8 cvt8(const float* __restrict__ p) {
    float4 v0 = *(const float4*)p;
    float4 v1 = *(const float4*)(p + 4);
    shortx8 r;
    r[0] = bf16s(v0.x); r[1] = bf16s(v0.y); r[2] = bf16s(v0.z); r[3] = bf16s(v0.w);
    r[4] = bf16s(v1.x); r[5] = bf16s(v1.y); r[6] = bf16s(v1.z); r[7] = bf16s(v1.w);
    return r;
}

// ---------------------------------------------------------------------------
// fp32 -> bf16 weight conversion (one-time per launch). n % 4 == 0.
// ---------------------------------------------------------------------------
__global__ __launch_bounds__(256) void cvt_f32_bf16(
    const float* __restrict__ src, __hip_bfloat16* __restrict__ dst, int n)
{
    int i = (blockIdx.x * 256 + threadIdx.x) * 4;
    if (i < n) {
        float4 v = *(const float4*)(src + i);
        dst[i + 0] = __float2bfloat16(v.x);
        dst[i + 1] = __float2bfloat16(v.y);
        dst[i + 2] = __float2bfloat16(v.z);
        dst[i + 3] = __float2bfloat16(v.w);
    }
}

// ---------------------------------------------------------------------------
// Kernel 1: x-part gate pre-activations for a chunk of T time steps (verified).
// Gx[(t-t0)*B + b][g*1024+j] = sum_k x[b][t][k] * Wg[j][1024+k] + bias_g[j]
// grid = T*8 blocks of 256.
// ---------------------------------------------------------------------------
__global__ __launch_bounds__(256) void gemm_gx(
    const float* __restrict__ x,
    const __hip_bfloat16* __restrict__ Wb,     // [4][1024][2048] bf16
    const float* __restrict__ bf_, const float* __restrict__ bi_,
    const float* __restrict__ bc_, const float* __restrict__ bo_,
    __hip_bfloat16* __restrict__ Gx, const int t0)
{
    const int wave = (blockIdx.x << 2) + (threadIdx.x >> 6);
    const int mt = wave >> 6;
    const int nt = wave & 63;
    const int lane = threadIdx.x & 63;
    const int quad = lane >> 4;
    const int l16  = lane & 15;
    const int m0 = mt << 6;
    const int n0 = nt << 6;
    const int g  = n0 >> 10;
    const __hip_bfloat16* Wg = Wb + (size_t)g * WG_ELEMS;
    const float* bg = (g == 0) ? bf_ : (g == 1) ? bi_ : (g == 2) ? bc_ : bo_;
    const int j0 = n0 & 1023;

    floatx4 acc[4][4];
#pragma unroll
    for (int i = 0; i < 4; i++)
#pragma unroll
        for (int j = 0; j < 4; j++) acc[i][j] = (floatx4)(0.0f);

    const float* arow[4];
    const __hip_bfloat16* brow[4];
#pragma unroll
    for (int i = 0; i < 4; i++) {
        const int r = m0 + i * 16 + l16;
        const int t = t0 + (r >> 5);
        const int b = r & 31;
        arow[i] = x + ((size_t)b * SEQ + t) * IND + quad * 8;
    }
#pragma unroll
    for (int j = 0; j < 4; j++)
        brow[j] = Wg + (size_t)(j0 + j * 16 + l16) * ZD + HD + quad * 8;

    for (int k0 = 0; k0 < IND; k0 += 32) {
        shortx8 a[4], b[4];
#pragma unroll
        for (int i = 0; i < 4; i++) a[i] = cvt8(arow[i] + k0);
#pragma unroll
        for (int j = 0; j < 4; j++) b[j] = *(const shortx8*)(brow[j] + k0);
#pragma unroll
        for (int i = 0; i < 4; i++)
#pragma unroll
            for (int j = 0; j < 4; j++)
                acc[i][j] = MFMA16(a[i], b[j], acc[i][j]);
    }

#pragma unroll
    for (int j = 0; j < 4; j++) {
        const int n  = n0 + j * 16 + l16;
        const int jj = j0 + j * 16 + l16;
        const float bias = bg[jj];
#pragma unroll
        for (int i = 0; i < 4; i++) {
#pragma unroll
            for (int r = 0; r < 4; r++) {
                const int row = m0 + i * 16 + quad * 4 + r;
                Gx[(size_t)row * NG + n] = __float2bfloat16(acc[i][j][r] + bias);
            }
        }
    }
}

// ---------------------------------------------------------------------------
// Kernel 2 (FALLBACK, small-ws path): one LSTM time step, hs-direct h I/O.
// ---------------------------------------------------------------------------
__global__ __launch_bounds__(256) void lstm_step(
    const __hip_bfloat16* __restrict__ gx,
    const int t,
    const __hip_bfloat16* __restrict__ Wb,
    const __hip_bfloat16* __restrict__ hzero,  // [B][H] zeros
    float* __restrict__ c,
    __hip_bfloat16* __restrict__ hs)           // [B][S][H]
{
    const int jt = (blockIdx.x << 2) + (threadIdx.x >> 6);
    const int lane = threadIdx.x & 63;
    const int quad = lane >> 4;
    const int l16  = lane & 15;
    const int j0   = jt << 4;

    const __hip_bfloat16* hb;
    size_t rstride;
    if (t == 0) { hb = hzero; rstride = HD; }
    else        { hb = hs + (size_t)(t - 1) * HD; rstride = (size_t)SEQ * HD; }

    const __hip_bfloat16* wrow[4];
#pragma unroll
    for (int g = 0; g < 4; g++)
        wrow[g] = Wb + (size_t)g * WG_ELEMS + (size_t)(j0 + l16) * ZD + quad * 8;

    const __hip_bfloat16* hrow0 = hb + (size_t)l16 * rstride + quad * 8;
    const __hip_bfloat16* hrow1 = hb + (size_t)(16 + l16) * rstride + quad * 8;

    floatx4 acc[4][2];
#pragma unroll
    for (int g = 0; g < 4; g++) { acc[g][0] = (floatx4)(0.0f); acc[g][1] = (floatx4)(0.0f); }

    for (int k0 = 0; k0 < HD; k0 += 32) {
        shortx8 a0 = *(const shortx8*)(hrow0 + k0);
        shortx8 a1 = *(const shortx8*)(hrow1 + k0);
#pragma unroll
        for (int g = 0; g < 4; g++) {
            shortx8 bfrag = *(const shortx8*)(wrow[g] + k0);
            acc[g][0] = MFMA16(a0, bfrag, acc[g][0]);
            acc[g][1] = MFMA16(a1, bfrag, acc[g][1]);
        }
    }

    const int j = j0 + l16;
#pragma unroll
    for (int i = 0; i < 2; i++) {
#pragma unroll
        for (int r = 0; r < 4; r++) {
            const int bb = i * 16 + quad * 4 + r;
            const size_t gbase = (size_t)bb * NG + j;
            const float fp = acc[0][i][r] + __bfloat162float(gx[gbase + 0 * HD]);
            const float ip = acc[1][i][r] + __bfloat162float(gx[gbase + 1 * HD]);
            const float cp = acc[2][i][r] + __bfloat162float(gx[gbase + 2 * HD]);
            const float op = acc[3][i][r] + __bfloat162float(gx[gbase + 3 * HD]);
            const float fg = sigmoidf_(fp);
            const float ig = sigmoidf_(ip);
            const float cg = tanhf_(cp);
            const float og = sigmoidf_(op);
            const size_t ci = (size_t)bb * HD + j;
            const float cnew = ig * cg + fg * c[ci];
            const float hnew = og * tanhf_(cnew);
            c[ci] = cnew;
            hs[((size_t)bb * SEQ + t) * HD + j] = __float2bfloat16(hnew);
        }
    }
}

// ---------------------------------------------------------------------------
// Kernel 2' (FAST path): persistent windowed recurrence, v6.
// Compute structure = v3/v5: 128 blocks x 256 threads, block owns 8 j-cols
// x 4 gates (32 Wh rows) in registers/AGPRs, A-frags direct from global
// hs[t-1], 32 MFMA/wave in 2 chains, LDS acc transpose, pointwise.
//
// v5 (kept): no agent-release in the loop; hs stores are packed-u32 RELAXED
// agent-scope atomic stores (sc1 => coherence-point visible); flag store
// relaxed, ordered by the pre-s_barrier vmcnt(0) drain.
//
// v6 change: A-frag STAGING. All 32 loads issue back-to-back into a register
// array (one pipelined IF latency ~1k cy instead of ~4 serialized rounds at
// the old 8-deep interleave; VGPR_Count 88 proved Bfrag lived in AGPRs and
// only ~8-12 loads could be in flight). sched_barrier(0) pins every load
// above the first MFMA. launch_bounds(256,1) permits ~512 VGPR/thread and
// occupancy is 2 waves/CU regardless, so the extra ~128 VGPRs are free.
// MFMA order unchanged => bit-identical numerics vs v5.
// ---------------------------------------------------------------------------
__global__ __launch_bounds__(256, 1) void lstm_persist(
    const __hip_bfloat16* __restrict__ Wb,     // [4][1024][2048] bf16
    const __hip_bfloat16* __restrict__ Gx,     // window base [(tt)*B + b][NG]
    const int t0, const int T, const int ebase, // barrier epoch base
    const __hip_bfloat16* __restrict__ hzero,  // [B][H] zeros
    float* __restrict__ c_ws,                  // [PBLK*256] fp32
    __hip_bfloat16* __restrict__ hs,           // [B][S][H] bf16
    unsigned* __restrict__ bar)                // arrive[PBLK] slots, stride 16 u32
{
    __shared__ float accf[32 * 36 + 4];

    const int tid  = threadIdx.x;
    const int blk  = blockIdx.x;
    const int wv   = tid >> 6;
    const int lane = tid & 63;
    const int quad = lane >> 4;
    const int l16  = lane & 15;
    const int wm   = wv >> 1;        // batch-half tile
    const int wn   = wv & 1;         // col-half tile

    // --- B fragments, loaded once per launch ---
    // MFMA col l16 of this wave's tile <-> gate-row (g = lc&3, j = blk*8 + (lc>>2))
    shortx8 Bfrag[32];
    {
        const int lc = wn * 16 + l16;
        const int jj = lc >> 2, g = lc & 3;
        const __hip_bfloat16* wr =
            Wb + (size_t)g * WG_ELEMS + (size_t)(blk * 8 + jj) * ZD + quad * 8;
#pragma unroll
        for (int ks = 0; ks < 32; ks++)
            Bfrag[ks] = *(const shortx8*)(wr + ks * 32);
    }

    // pointwise mapping: 8 consecutive lanes = 8 consecutive j (16B store runs)
    const int pjj = tid & 7;
    const int pb  = tid >> 3;
    const int pj  = blk * 8 + pjj;
    float creg = c_ws[blk * 256 + tid];

    for (int tt = 0; tt < T; tt++) {
        const int t = t0 + tt;
        const __hip_bfloat16* hb;
        size_t rstride;
        if (t == 0) { hb = hzero; rstride = HD; }
        else        { hb = hs + (size_t)(t - 1) * HD; rstride = (size_t)SEQ * HD; }

        // gx pre-activations for (pb, pj) — issue early
        const __hip_bfloat16* gx = Gx + ((size_t)tt * BATCH + pb) * NG + pj;
        const float gxf = __bfloat162float(gx[0 * HD]);
        const float gxi = __bfloat162float(gx[1 * HD]);
        const float gxc = __bfloat162float(gx[2 * HD]);
        const float gxo = __bfloat162float(gx[3 * HD]);

        // h @ Wh^T : stage ALL 32 A-frags back-to-back (one pipelined IF
        // latency), sched_barrier pins the issue order, then 2 MFMA chains.
        const __hip_bfloat16* arow = hb + (size_t)(wm * 16 + l16) * rstride + quad * 8;
        shortx8 a[32];
#pragma unroll
        for (int ks = 0; ks < 32; ks++)
            a[ks] = *(const shortx8*)(arow + ks * 32);
        __builtin_amdgcn_sched_barrier(0);   // all loads issue above this line

        floatx4 acc0 = (floatx4)(0.0f), acc1 = (floatx4)(0.0f);
#pragma unroll
        for (int ks = 0; ks < 16; ks++) {
            acc0 = MFMA16(a[2 * ks],     Bfrag[2 * ks],     acc0);
            acc1 = MFMA16(a[2 * ks + 1], Bfrag[2 * ks + 1], acc1);
        }
        const floatx4 acc = acc0 + acc1;

        // acc -> LDS [col][b], stride 36 floats (16B-aligned, <=4-way)
        {
            const int col = wn * 16 + l16;
            const int b0  = wm * 16 + quad * 4;
            *(floatx4*)(accf + col * 36 + b0) = acc;
        }
        __syncthreads();

        // pointwise for (pb, pjj); c lives in a register across the window
        {
            const float fp = accf[(pjj * 4 + 0) * 36 + pb] + gxf;
            const float ip = accf[(pjj * 4 + 1) * 36 + pb] + gxi;
            const float cp = accf[(pjj * 4 + 2) * 36 + pb] + gxc;
            const float op = accf[(pjj * 4 + 3) * 36 + pb] + gxo;
            const float fg = sigmoidf_(fp);
            const float ig = sigmoidf_(ip);
            const float cg = tanhf_(cp);
            const float og = sigmoidf_(op);
            creg = ig * cg + fg * creg;
            const float hnew = og * tanhf_(creg);

            // packed-u32 relaxed agent store (sc1 => coherence-point visible).
            const unsigned my = (unsigned)(unsigned short)bf16s(hnew);
            const unsigned nb = (unsigned)__shfl_xor((int)my, 1);
            if ((tid & 1) == 0) {
                unsigned* dst = (unsigned*)(hs + ((size_t)pb * SEQ + t) * HD + pj);
                const unsigned packed = my | (nb << 16);
                __hip_atomic_store(dst, packed, __ATOMIC_RELAXED,
                                   __HIP_MEMORY_SCOPE_AGENT);
            }
        }

        // device barrier (not needed after the window's last step)
        if (tt < T - 1) {
            __syncthreads();   // per-wave s_waitcnt vmcnt(0): sc1 stores at IF
            const unsigned epoch = (unsigned)(ebase + tt + 1);
            if (wv == 0) {
                if (lane == 0) {
                    // relaxed signal — ordering already established by the
                    // pre-barrier vmcnt(0) drain of all waves' sc1 stores.
                    __hip_atomic_store(bar + blk * 16, epoch, __ATOMIC_RELAXED,
                                       __HIP_MEMORY_SCOPE_AGENT);
                }
                // parallel poll: lane L watches slots L and L+64
                unsigned* p0 = bar + lane * 16;
                unsigned* p1 = bar + (64 + lane) * 16;
                bool d0 = false, d1 = false;
                while (true) {
                    if (!d0) d0 = (__hip_atomic_load(p0, __ATOMIC_RELAXED,
                                       __HIP_MEMORY_SCOPE_AGENT) >= epoch);
                    if (!d1) d1 = (__hip_atomic_load(p1, __ATOMIC_RELAXED,
                                       __HIP_MEMORY_SCOPE_AGENT) >= epoch);
                    if (__all(d0 && d1)) break;
                    __builtin_amdgcn_s_sleep(1);
                }
                // compiler-level fence only: hs[t] lines are fresh addresses,
                // never cached by this XCD before their write (see header).
                asm volatile("" ::: "memory");
                __builtin_amdgcn_sched_barrier(0);
            }
            __syncthreads();
        }
    }

    c_ws[blk * 256 + tid] = creg;
}

// ---------------------------------------------------------------------------
// Kernel 3: out[r][n] = sum_k hs[r][k] * Wfc[n][k] + bfc[n]   (fp32 out)
// ---------------------------------------------------------------------------
__global__ __launch_bounds__(256) void gemm_fc(
    const __hip_bfloat16* __restrict__ hs,
    const __hip_bfloat16* __restrict__ Wfcb,
    const float* __restrict__ bfc,
    float* __restrict__ out)
{
    const int wave = (blockIdx.x << 2) + (threadIdx.x >> 6);
    const int mt = wave >> 4;
    const int nt = wave & 15;
    const int lane = threadIdx.x & 63;
    const int quad = lane >> 4;
    const int l16  = lane & 15;
    const int m0 = mt << 6;
    const int n0 = nt << 6;

    floatx4 acc[4][4];
#pragma unroll
    for (int i = 0; i < 4; i++)
#pragma unroll
        for (int j = 0; j < 4; j++) acc[i][j] = (floatx4)(0.0f);

    const __hip_bfloat16* arow[4];
    const __hip_bfloat16* brow[4];
#pragma unroll
    for (int i = 0; i < 4; i++)
        arow[i] = hs + (size_t)(m0 + i * 16 + l16) * HD + quad * 8;
#pragma unroll
    for (int j = 0; j < 4; j++)
        brow[j] = Wfcb + (size_t)(n0 + j * 16 + l16) * HD + quad * 8;

    for (int k0 = 0; k0 < HD; k0 += 32) {
        shortx8 a[4], b[4];
#pragma unroll
        for (int i = 0; i < 4; i++) a[i] = *(const shortx8*)(arow[i] + k0);
#pragma unroll
        for (int j = 0; j < 4; j++) b[j] = *(const shortx8*)(brow[j] + k0);
#pragma unroll
        for (int i = 0; i < 4; i++)
#pragma unroll
            for (int j = 0; j < 4; j++)
                acc[i][j] = MFMA16(a[i], b[j], acc[i][j]);
    }

#pragma unroll
    for (int j = 0; j < 4; j++) {
        const int n = n0 + j * 16 + l16;
        const float bias = bfc[n];
#pragma unroll
        for (int i = 0; i < 4; i++) {
#pragma unroll
            for (int r = 0; r < 4; r++) {
                const int row = m0 + i * 16 + quad * 4 + r;
                out[(size_t)row * 1024 + n] = acc[i][j][r] + bias;
            }
        }
    }
}

// ---------------------------------------------------------------------------
extern "C" void kernel_launch(void* const* d_in, const int* in_sizes, int n_in,
                              void* d_out, int out_size, void* d_ws, size_t ws_size,
                              hipStream_t stream) {
    const float* x   = (const float*)d_in[0];
    const float* Wf  = (const float*)d_in[1];
    const float* bf_ = (const float*)d_in[2];
    const float* Wi  = (const float*)d_in[3];
    const float* bi_ = (const float*)d_in[4];
    const float* Wc  = (const float*)d_in[5];
    const float* bc_ = (const float*)d_in[6];
    const float* Wo  = (const float*)d_in[7];
    const float* bo_ = (const float*)d_in[8];
    const float* Wfc = (const float*)d_in[9];
    const float* bfc = (const float*)d_in[10];
    float* out = (float*)d_out;

    // ---- ws layout (bytes) ----
    char* ws = (char*)d_ws;
    const size_t WB_OFF  = 0;                                          // 16 MiB
    const size_t WFC_OFF = (size_t)4 * WG_ELEMS * 2;                   // +2 MiB
    const size_t HS_OFF  = WFC_OFF + (size_t)HD * HD * 2;              // +32 MiB
    const size_t ST_OFF  = HS_OFF + (size_t)BATCH * SEQ * HD * 2;
    const size_t HZ_BYTES  = (size_t)BATCH * HD * 2;                   // 64 KiB
    const size_t C_BYTES   = (size_t)PBLK * 256 * 4;                   // 128 KiB
    const size_t BAR_BYTES = (size_t)PBLK * 64;                        // arrive slots
    const size_t ST_BYTES  = HZ_BYTES + C_BYTES + BAR_BYTES;
    const size_t GX_OFF  = ST_OFF + ST_BYTES;

    __hip_bfloat16* Wb    = (__hip_bfloat16*)(ws + WB_OFF);
    __hip_bfloat16* Wfcb  = (__hip_bfloat16*)(ws + WFC_OFF);
    __hip_bfloat16* hs    = (__hip_bfloat16*)(ws + HS_OFF);
    __hip_bfloat16* hzero = (__hip_bfloat16*)(ws + ST_OFF);
    float*          cbuf  = (float*)(ws + ST_OFF + HZ_BYTES);
    unsigned*       bar   = (unsigned*)(ws + ST_OFF + HZ_BYTES + C_BYTES);
    __hip_bfloat16* Gx    = (__hip_bfloat16*)(ws + GX_OFF);

    // pick path + largest time chunk that fits ws (deterministic per session)
    const size_t GX_STEP = (size_t)BATCH * NG * 2;   // 256 KiB per step
    int T_CHUNK = 1; int persist = 0;
    {
        const int popts[3] = {512, 128, 32};
        for (int i = 0; i < 3; i++) {
            if (GX_OFF + (size_t)popts[i] * GX_STEP <= ws_size) {
                T_CHUNK = popts[i]; persist = 1; break;
            }
        }
        if (!persist) {
            const int fopts[3] = {8, 2, 1};
            for (int i = 0; i < 3; i++) {
                if (GX_OFF + (size_t)fopts[i] * GX_STEP <= ws_size) {
                    T_CHUNK = fopts[i]; break;
                }
            }
        }
    }

    // one-time weight conversion fp32 -> bf16
    cvt_f32_bf16<<<2048, 256, 0, stream>>>(Wf, Wb + 0 * (size_t)WG_ELEMS, WG_ELEMS);
    cvt_f32_bf16<<<2048, 256, 0, stream>>>(Wi, Wb + 1 * (size_t)WG_ELEMS, WG_ELEMS);
    cvt_f32_bf16<<<2048, 256, 0, stream>>>(Wc, Wb + 2 * (size_t)WG_ELEMS, WG_ELEMS);
    cvt_f32_bf16<<<2048, 256, 0, stream>>>(Wo, Wb + 3 * (size_t)WG_ELEMS, WG_ELEMS);
    cvt_f32_bf16<<<1024, 256, 0, stream>>>(Wfc, Wfcb, HD * HD);

    // zero hzero, c, barrier state (ws poisoned 0xAA every launch)
    hipMemsetAsync(ws + ST_OFF, 0, ST_BYTES, stream);

    for (int t0 = 0; t0 < SEQ; t0 += T_CHUNK) {
        gemm_gx<<<T_CHUNK * 8, 256, 0, stream>>>(
            x, Wb, bf_, bi_, bc_, bo_, Gx, t0);
        if (persist) {
            const int ebase = (t0 / T_CHUNK) * (T_CHUNK - 1);
            lstm_persist<<<PBLK, 256, 0, stream>>>(
                Wb, Gx, t0, T_CHUNK, ebase, hzero, cbuf, hs, bar);
        } else {
            for (int t = t0; t < t0 + T_CHUNK; t++) {
                const __hip_bfloat16* gx_t = Gx + (size_t)(t - t0) * BATCH * NG;
                lstm_step<<<16, 256, 0, stream>>>(gx_t, t, Wb, hzero, cbuf, hs);
            }
        }
    }

    gemm_fc<<<1024, 256, 0, stream>>>(hs, Wfcb, bfc, out);
}

// Round 5
// 3365.878 us; speedup vs baseline: 1.1771x; 1.1771x over previous
//
#include <hip/hip_runtime.h>
#include <hip/hip_bf16.h>

#define BATCH 32
#define SEQ   512
#define IND   1024
#define HD    1024
#define ZD    2048   // IN + H
#define NG    4096   // 4*H
#define WG_ELEMS (1024 * 2048)   // elements per gate weight matrix
#define PBLK 128                 // persistent grid size

typedef short  shortx8 __attribute__((ext_vector_type(8)));
typedef float  floatx4 __attribute__((ext_vector_type(4)));

#define MFMA16(a, b, c) __builtin_amdgcn_mfma_f32_16x16x32_bf16((a), (b), (c), 0, 0, 0)

__device__ __forceinline__ float sigmoidf_(float x) {
    return 1.0f / (1.0f + __expf(-x));
}
__device__ __forceinline__ float tanhf_(float x) {
    return 1.0f - 2.0f / (__expf(2.0f * x) + 1.0f);
}

__device__ __forceinline__ short bf16s(float x) {
    __hip_bfloat16 h = __float2bfloat16(x);
    return *reinterpret_cast<short*>(&h);
}

__device__ __forceinline__ float bf2f(unsigned short u) {
    unsigned v = ((unsigned)u) << 16;
    float f;
    __builtin_memcpy(&f, &v, 4);
    return f;
}

__device__ __forceinline__ shortx8 cvt8(const float* __restrict__ p) {
    float4 v0 = *(const float4*)p;
    float4 v1 = *(const float4*)(p + 4);
    shortx8 r;
    r[0] = bf16s(v0.x); r[1] = bf16s(v0.y); r[2] = bf16s(v0.z); r[3] = bf16s(v0.w);
    r[4] = bf16s(v1.x); r[5] = bf16s(v1.y); r[6] = bf16s(v1.z); r[7] = bf16s(v1.w);
    return r;
}

// ---------------------------------------------------------------------------
// fp32 -> bf16 weight conversion (one-time per launch). n % 4 == 0.
// ---------------------------------------------------------------------------
__global__ __launch_bounds__(256) void cvt_f32_bf16(
    const float* __restrict__ src, __hip_bfloat16* __restrict__ dst, int n)
{
    int i = (blockIdx.x * 256 + threadIdx.x) * 4;
    if (i < n) {
        float4 v = *(const float4*)(src + i);
        dst[i + 0] = __float2bfloat16(v.x);
        dst[i + 1] = __float2bfloat16(v.y);
        dst[i + 2] = __float2bfloat16(v.z);
        dst[i + 3] = __float2bfloat16(v.w);
    }
}

// ---------------------------------------------------------------------------
// Kernel 1: x-part gate pre-activations for a chunk of T time steps (verified).
// Gx[(t-t0)*B + b][g*1024+j] = sum_k x[b][t][k] * Wg[j][1024+k] + bias_g[j]
// grid = T*8 blocks of 256.
// ---------------------------------------------------------------------------
__global__ __launch_bounds__(256) void gemm_gx(
    const float* __restrict__ x,
    const __hip_bfloat16* __restrict__ Wb,     // [4][1024][2048] bf16
    const float* __restrict__ bf_, const float* __restrict__ bi_,
    const float* __restrict__ bc_, const float* __restrict__ bo_,
    __hip_bfloat16* __restrict__ Gx, const int t0)
{
    const int wave = (blockIdx.x << 2) + (threadIdx.x >> 6);
    const int mt = wave >> 6;
    const int nt = wave & 63;
    const int lane = threadIdx.x & 63;
    const int quad = lane >> 4;
    const int l16  = lane & 15;
    const int m0 = mt << 6;
    const int n0 = nt << 6;
    const int g  = n0 >> 10;
    const __hip_bfloat16* Wg = Wb + (size_t)g * WG_ELEMS;
    const float* bg = (g == 0) ? bf_ : (g == 1) ? bi_ : (g == 2) ? bc_ : bo_;
    const int j0 = n0 & 1023;

    floatx4 acc[4][4];
#pragma unroll
    for (int i = 0; i < 4; i++)
#pragma unroll
        for (int j = 0; j < 4; j++) acc[i][j] = (floatx4)(0.0f);

    const float* arow[4];
    const __hip_bfloat16* brow[4];
#pragma unroll
    for (int i = 0; i < 4; i++) {
        const int r = m0 + i * 16 + l16;
        const int t = t0 + (r >> 5);
        const int b = r & 31;
        arow[i] = x + ((size_t)b * SEQ + t) * IND + quad * 8;
    }
#pragma unroll
    for (int j = 0; j < 4; j++)
        brow[j] = Wg + (size_t)(j0 + j * 16 + l16) * ZD + HD + quad * 8;

    for (int k0 = 0; k0 < IND; k0 += 32) {
        shortx8 a[4], b[4];
#pragma unroll
        for (int i = 0; i < 4; i++) a[i] = cvt8(arow[i] + k0);
#pragma unroll
        for (int j = 0; j < 4; j++) b[j] = *(const shortx8*)(brow[j] + k0);
#pragma unroll
        for (int i = 0; i < 4; i++)
#pragma unroll
            for (int j = 0; j < 4; j++)
                acc[i][j] = MFMA16(a[i], b[j], acc[i][j]);
    }

#pragma unroll
    for (int j = 0; j < 4; j++) {
        const int n  = n0 + j * 16 + l16;
        const int jj = j0 + j * 16 + l16;
        const float bias = bg[jj];
#pragma unroll
        for (int i = 0; i < 4; i++) {
#pragma unroll
            for (int r = 0; r < 4; r++) {
                const int row = m0 + i * 16 + quad * 4 + r;
                Gx[(size_t)row * NG + n] = __float2bfloat16(acc[i][j][r] + bias);
            }
        }
    }
}

// ---------------------------------------------------------------------------
// Kernel 2 (FALLBACK, small-ws path): one LSTM time step, hs-direct h I/O.
// ---------------------------------------------------------------------------
__global__ __launch_bounds__(256) void lstm_step(
    const __hip_bfloat16* __restrict__ gx,
    const int t,
    const __hip_bfloat16* __restrict__ Wb,
    const __hip_bfloat16* __restrict__ hzero,  // [B][H] zeros
    float* __restrict__ c,
    __hip_bfloat16* __restrict__ hs)           // [B][S][H]
{
    const int jt = (blockIdx.x << 2) + (threadIdx.x >> 6);
    const int lane = threadIdx.x & 63;
    const int quad = lane >> 4;
    const int l16  = lane & 15;
    const int j0   = jt << 4;

    const __hip_bfloat16* hb;
    size_t rstride;
    if (t == 0) { hb = hzero; rstride = HD; }
    else        { hb = hs + (size_t)(t - 1) * HD; rstride = (size_t)SEQ * HD; }

    const __hip_bfloat16* wrow[4];
#pragma unroll
    for (int g = 0; g < 4; g++)
        wrow[g] = Wb + (size_t)g * WG_ELEMS + (size_t)(j0 + l16) * ZD + quad * 8;

    const __hip_bfloat16* hrow0 = hb + (size_t)l16 * rstride + quad * 8;
    const __hip_bfloat16* hrow1 = hb + (size_t)(16 + l16) * rstride + quad * 8;

    floatx4 acc[4][2];
#pragma unroll
    for (int g = 0; g < 4; g++) { acc[g][0] = (floatx4)(0.0f); acc[g][1] = (floatx4)(0.0f); }

    for (int k0 = 0; k0 < HD; k0 += 32) {
        shortx8 a0 = *(const shortx8*)(hrow0 + k0);
        shortx8 a1 = *(const shortx8*)(hrow1 + k0);
#pragma unroll
        for (int g = 0; g < 4; g++) {
            shortx8 bfrag = *(const shortx8*)(wrow[g] + k0);
            acc[g][0] = MFMA16(a0, bfrag, acc[g][0]);
            acc[g][1] = MFMA16(a1, bfrag, acc[g][1]);
        }
    }

    const int j = j0 + l16;
#pragma unroll
    for (int i = 0; i < 2; i++) {
#pragma unroll
        for (int r = 0; r < 4; r++) {
            const int bb = i * 16 + quad * 4 + r;
            const size_t gbase = (size_t)bb * NG + j;
            const float fp = acc[0][i][r] + __bfloat162float(gx[gbase + 0 * HD]);
            const float ip = acc[1][i][r] + __bfloat162float(gx[gbase + 1 * HD]);
            const float cp = acc[2][i][r] + __bfloat162float(gx[gbase + 2 * HD]);
            const float op = acc[3][i][r] + __bfloat162float(gx[gbase + 3 * HD]);
            const float fg = sigmoidf_(fp);
            const float ig = sigmoidf_(ip);
            const float cg = tanhf_(cp);
            const float og = sigmoidf_(op);
            const size_t ci = (size_t)bb * HD + j;
            const float cnew = ig * cg + fg * c[ci];
            const float hnew = og * tanhf_(cnew);
            c[ci] = cnew;
            hs[((size_t)bb * SEQ + t) * HD + j] = __float2bfloat16(hnew);
        }
    }
}

// ---------------------------------------------------------------------------
// Kernel 2' (FAST path): persistent windowed recurrence, v7.
// 128 blocks x 256 threads. Wave (wm = batch-half, wk = K-half); each wave
// computes BOTH 16-col tiles (2 independent MFMA chains sharing one A-frag)
// over K=512. This removes the v3/v5 wn-duplication of A reads: 16 A-loads
// per wave instead of 32 => per-block L1 return traffic for h halves
// (128KB -> 64KB per step). wk partials reduced via 2-panel LDS in the
// pointwise (v4's reduce, but at 256 threads which is the proven-best
// block shape).
//
// Gx software pipeline: step tt+1's four gx values are loaded (raw u16, in
// registers) at the top of iteration tt, completing under the MFMA phase
// ~4us before use. Removes Gx HBM latency/jitter from the post-barrier
// critical path and from the pre-flag store drain (straggler convoy
// mitigation: per-step time is the max over 128 blocks).
//
// v5 (kept): no agent-release in the loop; hs stores are packed-u32 RELAXED
// agent-scope atomic stores (sc1 => coherence-point visible); flag store
// relaxed, ordered by the pre-s_barrier vmcnt(0) drain; distributed
// arrive-flag array + parallel lane poll with sticky done bits.
// ---------------------------------------------------------------------------
__global__ __launch_bounds__(256, 1) void lstm_persist(
    const __hip_bfloat16* __restrict__ Wb,     // [4][1024][2048] bf16
    const __hip_bfloat16* __restrict__ Gx,     // window base [(tt)*B + b][NG]
    const int t0, const int T, const int ebase, // barrier epoch base
    const __hip_bfloat16* __restrict__ hzero,  // [B][H] zeros
    float* __restrict__ c_ws,                  // [PBLK*256] fp32
    __hip_bfloat16* __restrict__ hs,           // [B][S][H] bf16
    unsigned* __restrict__ bar)                // arrive[PBLK] slots, stride 16 u32
{
    // two wk-partial panels: [wk][col*36 + b], panel stride 1168 (16B-aligned)
    __shared__ float accf[2 * 1168];

    const int tid  = threadIdx.x;
    const int blk  = blockIdx.x;
    const int wv   = tid >> 6;
    const int lane = tid & 63;
    const int quad = lane >> 4;
    const int l16  = lane & 15;
    const int wm   = wv & 1;         // batch-half tile
    const int wk   = wv >> 1;        // K-half

    // --- B fragments, loaded once per launch ---
    // col (= ct*16 + l16, 0..31) <-> gate-row (g = col&3, j = blk*8 + (col>>2))
    shortx8 Bfrag[2][16];
#pragma unroll
    for (int ct = 0; ct < 2; ct++) {
        const int lc = ct * 16 + l16;
        const int jj = lc >> 2, g = lc & 3;
        const __hip_bfloat16* wr =
            Wb + (size_t)g * WG_ELEMS + (size_t)(blk * 8 + jj) * ZD + wk * 512 + quad * 8;
#pragma unroll
        for (int ks = 0; ks < 16; ks++)
            Bfrag[ct][ks] = *(const shortx8*)(wr + ks * 32);
    }

    // pointwise mapping: 8 consecutive lanes = 8 consecutive j
    const int pjj = tid & 7;
    const int pb  = tid >> 3;
    const int pj  = blk * 8 + pjj;
    float creg = c_ws[blk * 256 + tid];

    // gx pipeline prologue: raw bf16 for step 0
    unsigned short gxr0, gxr1, gxr2, gxr3;
    {
        const __hip_bfloat16* gx = Gx + (size_t)pb * NG + pj;
        gxr0 = *(const unsigned short*)(gx + 0 * HD);
        gxr1 = *(const unsigned short*)(gx + 1 * HD);
        gxr2 = *(const unsigned short*)(gx + 2 * HD);
        gxr3 = *(const unsigned short*)(gx + 3 * HD);
    }

    for (int tt = 0; tt < T; tt++) {
        const int t = t0 + tt;
        const __hip_bfloat16* hb;
        size_t rstride;
        if (t == 0) { hb = hzero; rstride = HD; }
        else        { hb = hs + (size_t)(t - 1) * HD; rstride = (size_t)SEQ * HD; }

        // issue NEXT step's gx loads early — complete under the MFMA phase
        unsigned short ngxr0 = 0, ngxr1 = 0, ngxr2 = 0, ngxr3 = 0;
        if (tt + 1 < T) {
            const __hip_bfloat16* gx1 = Gx + ((size_t)(tt + 1) * BATCH + pb) * NG + pj;
            ngxr0 = *(const unsigned short*)(gx1 + 0 * HD);
            ngxr1 = *(const unsigned short*)(gx1 + 1 * HD);
            ngxr2 = *(const unsigned short*)(gx1 + 2 * HD);
            ngxr3 = *(const unsigned short*)(gx1 + 3 * HD);
        }

        // h @ Wh^T : one A-frag stream feeds BOTH col-tile chains
        const __hip_bfloat16* arow =
            hb + (size_t)(wm * 16 + l16) * rstride + wk * 512 + quad * 8;
        floatx4 acc0 = (floatx4)(0.0f), acc1 = (floatx4)(0.0f);
#pragma unroll
        for (int ks = 0; ks < 16; ks++) {
            shortx8 av = *(const shortx8*)(arow + ks * 32);
            acc0 = MFMA16(av, Bfrag[0][ks], acc0);
            acc1 = MFMA16(av, Bfrag[1][ks], acc1);
        }

        // acc -> LDS [wk][col][b], stride 36 floats (16B-aligned)
        {
            const int b0 = wm * 16 + quad * 4;
            *(floatx4*)(accf + wk * 1168 + (l16)      * 36 + b0) = acc0;
            *(floatx4*)(accf + wk * 1168 + (16 + l16) * 36 + b0) = acc1;
        }
        __syncthreads();

        // pointwise for (pb, pjj); c lives in a register across the window
        {
            const int i0 = (pjj * 4 + 0) * 36 + pb;
            const int i1 = (pjj * 4 + 1) * 36 + pb;
            const int i2 = (pjj * 4 + 2) * 36 + pb;
            const int i3 = (pjj * 4 + 3) * 36 + pb;
            const float fp = accf[i0] + accf[1168 + i0] + bf2f(gxr0);
            const float ip = accf[i1] + accf[1168 + i1] + bf2f(gxr1);
            const float cp = accf[i2] + accf[1168 + i2] + bf2f(gxr2);
            const float op = accf[i3] + accf[1168 + i3] + bf2f(gxr3);
            const float fg = sigmoidf_(fp);
            const float ig = sigmoidf_(ip);
            const float cg = tanhf_(cp);
            const float og = sigmoidf_(op);
            creg = ig * cg + fg * creg;
            const float hnew = og * tanhf_(creg);

            // packed-u32 relaxed agent store (sc1 => coherence-point visible).
            const unsigned my = (unsigned)(unsigned short)bf16s(hnew);
            const unsigned nb = (unsigned)__shfl_xor((int)my, 1);
            if ((tid & 1) == 0) {
                unsigned* dst = (unsigned*)(hs + ((size_t)pb * SEQ + t) * HD + pj);
                const unsigned packed = my | (nb << 16);
                __hip_atomic_store(dst, packed, __ATOMIC_RELAXED,
                                   __HIP_MEMORY_SCOPE_AGENT);
            }
        }

        // device barrier (not needed after the window's last step)
        if (tt < T - 1) {
            __syncthreads();   // per-wave s_waitcnt vmcnt(0): sc1 stores at IF
            const unsigned epoch = (unsigned)(ebase + tt + 1);
            if (wv == 0) {
                if (lane == 0) {
                    // relaxed signal — ordering already established by the
                    // pre-barrier vmcnt(0) drain of all waves' sc1 stores.
                    __hip_atomic_store(bar + blk * 16, epoch, __ATOMIC_RELAXED,
                                       __HIP_MEMORY_SCOPE_AGENT);
                }
                // parallel poll: lane L watches slots L and L+64 (sticky)
                unsigned* p0 = bar + lane * 16;
                unsigned* p1 = bar + (64 + lane) * 16;
                bool d0 = false, d1 = false;
                while (true) {
                    if (!d0) d0 = (__hip_atomic_load(p0, __ATOMIC_RELAXED,
                                       __HIP_MEMORY_SCOPE_AGENT) >= epoch);
                    if (!d1) d1 = (__hip_atomic_load(p1, __ATOMIC_RELAXED,
                                       __HIP_MEMORY_SCOPE_AGENT) >= epoch);
                    if (__all(d0 && d1)) break;
                    __builtin_amdgcn_s_sleep(1);
                }
                // compiler-level fence only: hs[t] lines are fresh addresses,
                // never cached by this XCD before their write (see header).
                asm volatile("" ::: "memory");
                __builtin_amdgcn_sched_barrier(0);
            }
            __syncthreads();
        }

        gxr0 = ngxr0; gxr1 = ngxr1; gxr2 = ngxr2; gxr3 = ngxr3;
    }

    c_ws[blk * 256 + tid] = creg;
}

// ---------------------------------------------------------------------------
// Kernel 3: out[r][n] = sum_k hs[r][k] * Wfc[n][k] + bfc[n]   (fp32 out)
// ---------------------------------------------------------------------------
__global__ __launch_bounds__(256) void gemm_fc(
    const __hip_bfloat16* __restrict__ hs,
    const __hip_bfloat16* __restrict__ Wfcb,
    const float* __restrict__ bfc,
    float* __restrict__ out)
{
    const int wave = (blockIdx.x << 2) + (threadIdx.x >> 6);
    const int mt = wave >> 4;
    const int nt = wave & 15;
    const int lane = threadIdx.x & 63;
    const int quad = lane >> 4;
    const int l16  = lane & 15;
    const int m0 = mt << 6;
    const int n0 = nt << 6;

    floatx4 acc[4][4];
#pragma unroll
    for (int i = 0; i < 4; i++)
#pragma unroll
        for (int j = 0; j < 4; j++) acc[i][j] = (floatx4)(0.0f);

    const __hip_bfloat16* arow[4];
    const __hip_bfloat16* brow[4];
#pragma unroll
    for (int i = 0; i < 4; i++)
        arow[i] = hs + (size_t)(m0 + i * 16 + l16) * HD + quad * 8;
#pragma unroll
    for (int j = 0; j < 4; j++)
        brow[j] = Wfcb + (size_t)(n0 + j * 16 + l16) * HD + quad * 8;

    for (int k0 = 0; k0 < HD; k0 += 32) {
        shortx8 a[4], b[4];
#pragma unroll
        for (int i = 0; i < 4; i++) a[i] = *(const shortx8*)(arow[i] + k0);
#pragma unroll
        for (int j = 0; j < 4; j++) b[j] = *(const shortx8*)(brow[j] + k0);
#pragma unroll
        for (int i = 0; i < 4; i++)
#pragma unroll
            for (int j = 0; j < 4; j++)
                acc[i][j] = MFMA16(a[i], b[j], acc[i][j]);
    }

#pragma unroll
    for (int j = 0; j < 4; j++) {
        const int n = n0 + j * 16 + l16;
        const float bias = bfc[n];
#pragma unroll
        for (int i = 0; i < 4; i++) {
#pragma unroll
            for (int r = 0; r < 4; r++) {
                const int row = m0 + i * 16 + quad * 4 + r;
                out[(size_t)row * 1024 + n] = acc[i][j][r] + bias;
            }
        }
    }
}

// ---------------------------------------------------------------------------
extern "C" void kernel_launch(void* const* d_in, const int* in_sizes, int n_in,
                              void* d_out, int out_size, void* d_ws, size_t ws_size,
                              hipStream_t stream) {
    const float* x   = (const float*)d_in[0];
    const float* Wf  = (const float*)d_in[1];
    const float* bf_ = (const float*)d_in[2];
    const float* Wi  = (const float*)d_in[3];
    const float* bi_ = (const float*)d_in[4];
    const float* Wc  = (const float*)d_in[5];
    const float* bc_ = (const float*)d_in[6];
    const float* Wo  = (const float*)d_in[7];
    const float* bo_ = (const float*)d_in[8];
    const float* Wfc = (const float*)d_in[9];
    const float* bfc = (const float*)d_in[10];
    float* out = (float*)d_out;

    // ---- ws layout (bytes) ----
    char* ws = (char*)d_ws;
    const size_t WB_OFF  = 0;                                          // 16 MiB
    const size_t WFC_OFF = (size_t)4 * WG_ELEMS * 2;                   // +2 MiB
    const size_t HS_OFF  = WFC_OFF + (size_t)HD * HD * 2;              // +32 MiB
    const size_t ST_OFF  = HS_OFF + (size_t)BATCH * SEQ * HD * 2;
    const size_t HZ_BYTES  = (size_t)BATCH * HD * 2;                   // 64 KiB
    const size_t C_BYTES   = (size_t)PBLK * 256 * 4;                   // 128 KiB
    const size_t BAR_BYTES = (size_t)PBLK * 64;                        // arrive slots
    const size_t ST_BYTES  = HZ_BYTES + C_BYTES + BAR_BYTES;
    const size_t GX_OFF  = ST_OFF + ST_BYTES;

    __hip_bfloat16* Wb    = (__hip_bfloat16*)(ws + WB_OFF);
    __hip_bfloat16* Wfcb  = (__hip_bfloat16*)(ws + WFC_OFF);
    __hip_bfloat16* hs    = (__hip_bfloat16*)(ws + HS_OFF);
    __hip_bfloat16* hzero = (__hip_bfloat16*)(ws + ST_OFF);
    float*          cbuf  = (float*)(ws + ST_OFF + HZ_BYTES);
    unsigned*       bar   = (unsigned*)(ws + ST_OFF + HZ_BYTES + C_BYTES);
    __hip_bfloat16* Gx    = (__hip_bfloat16*)(ws + GX_OFF);

    // pick path + largest time chunk that fits ws (deterministic per session)
    const size_t GX_STEP = (size_t)BATCH * NG * 2;   // 256 KiB per step
    int T_CHUNK = 1; int persist = 0;
    {
        const int popts[3] = {512, 128, 32};
        for (int i = 0; i < 3; i++) {
            if (GX_OFF + (size_t)popts[i] * GX_STEP <= ws_size) {
                T_CHUNK = popts[i]; persist = 1; break;
            }
        }
        if (!persist) {
            const int fopts[3] = {8, 2, 1};
            for (int i = 0; i < 3; i++) {
                if (GX_OFF + (size_t)fopts[i] * GX_STEP <= ws_size) {
                    T_CHUNK = fopts[i]; break;
                }
            }
        }
    }

    // one-time weight conversion fp32 -> bf16
    cvt_f32_bf16<<<2048, 256, 0, stream>>>(Wf, Wb + 0 * (size_t)WG_ELEMS, WG_ELEMS);
    cvt_f32_bf16<<<2048, 256, 0, stream>>>(Wi, Wb + 1 * (size_t)WG_ELEMS, WG_ELEMS);
    cvt_f32_bf16<<<2048, 256, 0, stream>>>(Wc, Wb + 2 * (size_t)WG_ELEMS, WG_ELEMS);
    cvt_f32_bf16<<<2048, 256, 0, stream>>>(Wo, Wb + 3 * (size_t)WG_ELEMS, WG_ELEMS);
    cvt_f32_bf16<<<1024, 256, 0, stream>>>(Wfc, Wfcb, HD * HD);

    // zero hzero, c, barrier state (ws poisoned 0xAA every launch)
    hipMemsetAsync(ws + ST_OFF, 0, ST_BYTES, stream);

    for (int t0 = 0; t0 < SEQ; t0 += T_CHUNK) {
        gemm_gx<<<T_CHUNK * 8, 256, 0, stream>>>(
            x, Wb, bf_, bi_, bc_, bo_, Gx, t0);
        if (persist) {
            const int ebase = (t0 / T_CHUNK) * (T_CHUNK - 1);
            lstm_persist<<<PBLK, 256, 0, stream>>>(
                Wb, Gx, t0, T_CHUNK, ebase, hzero, cbuf, hs, bar);
        } else {
            for (int t = t0; t < t0 + T_CHUNK; t++) {
                const __hip_bfloat16* gx_t = Gx + (size_t)(t - t0) * BATCH * NG;
                lstm_step<<<16, 256, 0, stream>>>(gx_t, t, Wb, hzero, cbuf, hs);
            }
        }
    }

    gemm_fc<<<1024, 256, 0, stream>>>(hs, Wfcb, bfc, out);
}